// Round 1
// baseline (2527.929 us; speedup 1.0000x reference)
//
#include <hip/hip_runtime.h>
#include <hip/hip_bf16.h>
#include <math.h>

// Decoder_62234076119175 — f32 correctness-first baseline.
// S=1024 E=4096 H=32 KVH=8 D=128 R=32 keep=512.
// Draft/top-k path deliberately kept in f32 end-to-end: selection must match
// numpy's f32 scores (bf16 would flip ~1000s of borderline top-k entries).

#define NEGBIG -1e30f

__device__ __forceinline__ unsigned int fkey(float f) {
    unsigned int u = __float_as_uint(f);
    return (u & 0x80000000u) ? ~u : (u | 0x80000000u);
}

// ---------------- RoPE tables: cos/sin[t][i], i in [0,64) ----------------
__global__ void rope_tables_kernel(float* __restrict__ cosb, float* __restrict__ sinb) {
    int t = blockIdx.x;
    int i = threadIdx.x; // 0..63
    double inv = pow(10000.0, -((double)(2 * i)) / 128.0);
    double ang = (double)t * inv;
    cosb[t * 64 + i] = (float)cos(ang);
    sinb[t * 64 + i] = (float)sin(ang);
}

// ---------------- 128x128 f32 GEMM tile, 256 thr, 8x8 regs -----------------
__device__ __forceinline__ void gemm128_tile(
    const float* __restrict__ A, const float* __restrict__ B, float* __restrict__ C,
    int Kdim, int N, int bm, int bn)
{
    __shared__ float As[8][128];
    __shared__ float Bs[8][128];
    const int t = threadIdx.x;
    const int tx = t & 15, ty = (t >> 4) & 15;

    float acc[8][8];
#pragma unroll
    for (int u = 0; u < 8; ++u)
#pragma unroll
        for (int w = 0; w < 8; ++w) acc[u][w] = 0.f;

    const int ai = t >> 1;          // 0..127 (A tile row)
    const int ah = (t & 1) * 4;     // k sub-offset
    const int bk = t >> 5;          // 0..7   (B tile k-row)
    const int bj = (t & 31) * 4;    // 0..124 (B tile col)

    const float* Ap = A + (size_t)(bm * 128 + ai) * Kdim + ah;
    const float* Bp = B + (size_t)bk * N + (size_t)bn * 128 + bj;

    for (int k0 = 0; k0 < Kdim; k0 += 8) {
        float4 av = *(const float4*)(Ap + k0);
        float4 bv = *(const float4*)(Bp + (size_t)k0 * N);
        __syncthreads();
        As[ah + 0][ai] = av.x;
        As[ah + 1][ai] = av.y;
        As[ah + 2][ai] = av.z;
        As[ah + 3][ai] = av.w;
        *(float4*)(&Bs[bk][bj]) = bv;
        __syncthreads();
#pragma unroll
        for (int kk = 0; kk < 8; ++kk) {
            float4 a0 = *(const float4*)(&As[kk][ty * 4]);
            float4 a1 = *(const float4*)(&As[kk][64 + ty * 4]);
            float4 b0 = *(const float4*)(&Bs[kk][tx * 4]);
            float4 b1 = *(const float4*)(&Bs[kk][64 + tx * 4]);
            float aa[8] = {a0.x, a0.y, a0.z, a0.w, a1.x, a1.y, a1.z, a1.w};
            float bb[8] = {b0.x, b0.y, b0.z, b0.w, b1.x, b1.y, b1.z, b1.w};
#pragma unroll
            for (int u = 0; u < 8; ++u)
#pragma unroll
                for (int w = 0; w < 8; ++w)
                    acc[u][w] = fmaf(aa[u], bb[w], acc[u][w]);
        }
    }
#pragma unroll
    for (int u = 0; u < 8; ++u) {
        int row = bm * 128 + ((u < 4) ? (ty * 4 + u) : (64 + ty * 4 + (u - 4)));
        float4 c0 = make_float4(acc[u][0], acc[u][1], acc[u][2], acc[u][3]);
        float4 c1 = make_float4(acc[u][4], acc[u][5], acc[u][6], acc[u][7]);
        *(float4*)(C + (size_t)row * N + (size_t)bn * 128 + tx * 4) = c0;
        *(float4*)(C + (size_t)row * N + (size_t)bn * 128 + 64 + tx * 4) = c1;
    }
}

// fused q/k/v projection: grid.x picks the weight/output pair
__global__ __launch_bounds__(256) void gemm_qkv_kernel(
    const float* __restrict__ hs, const float* __restrict__ wq,
    const float* __restrict__ wk, const float* __restrict__ wv,
    float* __restrict__ q, float* __restrict__ k, float* __restrict__ v)
{
    int bn = blockIdx.x, bm = blockIdx.y;
    const float* B; float* C; int N;
    if (bn < 32)      { B = wq; C = q; N = 4096; }
    else if (bn < 40) { B = wk; C = k; N = 1024; bn -= 32; }
    else              { B = wv; C = v; N = 1024; bn -= 40; }
    gemm128_tile(hs, B, C, 4096, N, bm, bn);
}

__global__ __launch_bounds__(256) void gemm_plain_kernel(
    const float* __restrict__ A, const float* __restrict__ B, float* __restrict__ C,
    int Kdim, int N)
{
    gemm128_tile(A, B, C, Kdim, N, blockIdx.y, blockIdx.x);
}

// ---------------- lrq/lrk = hs @ mixq / mixk  (f32, small) ----------------
__global__ __launch_bounds__(256) void lr_kernel(
    const float* __restrict__ hs, const float* __restrict__ mixq, const float* __restrict__ mixk,
    float* __restrict__ lrq, float* __restrict__ lrk)
{
    __shared__ float row[4096];
    __shared__ float part[2][32][4];
    int m = blockIdx.x, t = threadIdx.x;
#pragma unroll
    for (int u = 0; u < 4; ++u)
        ((float4*)row)[t + u * 256] = ((const float4*)(hs + (size_t)m * 4096))[t + u * 256];
    __syncthreads();
    int r = t & 31, which = (t >> 5) & 1, quarter = t >> 6;
    const float* mix = which ? mixk : mixq;
    float acc = 0.f;
    int kbase = quarter * 1024;
#pragma unroll 8
    for (int kk = 0; kk < 1024; ++kk)
        acc = fmaf(row[kbase + kk], mix[(size_t)(kbase + kk) * 32 + r], acc);
    part[which][r][quarter] = acc;
    __syncthreads();
    if (t < 64) {
        int r2 = t & 31, w2 = t >> 5;
        float s = part[w2][r2][0] + part[w2][r2][1] + part[w2][r2][2] + part[w2][r2][3];
        (w2 ? lrk : lrq)[(size_t)m * 32 + r2] = s;
    }
}

// ---------------- pq/pk[h][m][d] = sum_r lr[m][r] * pos[m][h][r][d] --------
__global__ __launch_bounds__(128) void ppos_kernel(
    const float* __restrict__ lr, const float* __restrict__ pos, float* __restrict__ out)
{
    int h = blockIdx.x, m = blockIdx.y, d = threadIdx.x;
    __shared__ float lrs[32];
    if (d < 32) lrs[d] = lr[(size_t)m * 32 + d];
    __syncthreads();
    const float* base = pos + ((size_t)(m * 32 + h) * 32) * 128 + d;
    float acc = 0.f;
#pragma unroll
    for (int r = 0; r < 32; ++r)
        acc = fmaf(lrs[r], base[(size_t)r * 128], acc);
    out[((size_t)h * 1024 + m) * 128 + d] = acc;
}

// ---------------- draft score + exact top-512 radix select -----------------
// block = (qtile of 16 rows, head). Each thread owns row i = t/16 and the 64
// columns j ≡ (t%16) (mod 16). Selection entirely in registers.
__global__ __launch_bounds__(256) void draft_select_kernel(
    const float* __restrict__ pq, const float* __restrict__ pk,
    unsigned long long* __restrict__ mask)
{
    int qt = blockIdx.x, h = blockIdx.y;
    int q0 = qt * 16;
    int t = threadIdx.x;
    __shared__ float pqs[16][132];
    __shared__ float pks[32][132];

    const float* pqh = pq + ((size_t)h * 1024 + q0) * 128;
    const float* pkh = pk + (size_t)h * 1024 * 128;

#pragma unroll
    for (int u = 0; u < 2; ++u) {
        int f4 = t + u * 256;
        int row = f4 >> 5, dg = (f4 & 31) * 4;
        *(float4*)(&pqs[row][dg]) = *(const float4*)(pqh + (size_t)row * 128 + dg);
    }

    int i = t >> 4, jj = t & 15;
    int qrow = q0 + i;
    unsigned int vals[64];

#pragma unroll
    for (int c = 0; c < 32; ++c) {
        __syncthreads();
#pragma unroll
        for (int u = 0; u < 4; ++u) {
            int f4 = t + u * 256;
            int row = f4 >> 5, dg = (f4 & 31) * 4;
            *(float4*)(&pks[row][dg]) = *(const float4*)(pkh + (size_t)(c * 32 + row) * 128 + dg);
        }
        __syncthreads();
        float s0 = 0.f, s1 = 0.f;
#pragma unroll
        for (int d = 0; d < 128; d += 4) {
            float4 a  = *(const float4*)(&pqs[i][d]);
            float4 b0 = *(const float4*)(&pks[jj][d]);
            float4 b1 = *(const float4*)(&pks[jj + 16][d]);
            s0 += a.x * b0.x + a.y * b0.y + a.z * b0.z + a.w * b0.w;
            s1 += a.x * b1.x + a.y * b1.y + a.z * b1.z + a.w * b1.w;
        }
        int j0 = c * 32 + jj, j1 = j0 + 16;
        vals[2 * c]     = fkey(j0 <= qrow ? s0 : NEGBIG);
        vals[2 * c + 1] = fkey(j1 <= qrow ? s1 : NEGBIG);
    }

    // radix select the 512-th largest key of this row (16 lanes cooperate)
    unsigned int p = 0u;
    int kth = 512;
    for (int b = 31; b >= 0; --b) {
        unsigned int bit = 1u << b;
        unsigned int himask = (b == 31) ? 0u : (0xFFFFFFFFu << (b + 1));
        int cnt = 0;
#pragma unroll
        for (int n = 0; n < 64; ++n)
            cnt += (int)((((vals[n] ^ p) & himask) == 0u) && ((vals[n] & bit) != 0u));
        cnt += __shfl_xor(cnt, 1);
        cnt += __shfl_xor(cnt, 2);
        cnt += __shfl_xor(cnt, 4);
        cnt += __shfl_xor(cnt, 8);
        if (cnt >= kth) p |= bit; else kth -= cnt;
    }

    // build 1024-bit keep mask (16 u64 words) via lane-OR reduction
    unsigned long long wpart[16];
#pragma unroll
    for (int w = 0; w < 16; ++w) wpart[w] = 0ull;
#pragma unroll
    for (int n = 0; n < 64; ++n) {
        int w = n >> 2;
        int bpos = jj + ((n & 3) << 4);   // col = 64*w + bpos
        wpart[w] |= ((unsigned long long)(vals[n] >= p)) << bpos;
    }
#pragma unroll
    for (int s = 1; s < 16; s <<= 1) {
#pragma unroll
        for (int w = 0; w < 16; ++w)
            wpart[w] |= __shfl_xor(wpart[w], s);
    }
    mask[((size_t)h * 1024 + qrow) * 16 + jj] = wpart[jj];
}

// ---------------- masked flash attention with on-the-fly RoPE --------------
__global__ __launch_bounds__(256) void attn_kernel(
    const float* __restrict__ q, const float* __restrict__ k, const float* __restrict__ v,
    const float* __restrict__ cosb, const float* __restrict__ sinb,
    const unsigned long long* __restrict__ mask, float* __restrict__ attn)
{
    int qt = blockIdx.x, h = blockIdx.y;
    int q0 = qt * 16;
    int kvh = h >> 2;
    int t = threadIdx.x;
    __shared__ float qrs[16][132];
    __shared__ float krs[32][132];
    __shared__ float vs[32][132];

#pragma unroll
    for (int u = 0; u < 8; ++u) {
        int e = t + u * 256;
        int row = e >> 7, d = e & 127;
        int pos = q0 + row;
        float x  = q[(size_t)pos * 4096 + h * 128 + d];
        float x2 = q[(size_t)pos * 4096 + h * 128 + (d ^ 64)];
        float cs = cosb[pos * 64 + (d & 63)];
        float sn = sinb[pos * 64 + (d & 63)];
        float rot = (d < 64) ? -x2 : x2;
        qrs[row][d] = (x * cs + rot * sn) * 0.08838834764831845f; // 1/sqrt(128)
    }

    int i = t >> 4, jj = t & 15;
    int rbase = (t & 63) & ~15;     // wave-lane base of this row's 16-lane group
    int qrow = q0 + i;
    float m_run = -3.0e38f, l_run = 0.f;
    float o[8];
#pragma unroll
    for (int u = 0; u < 8; ++u) o[u] = 0.f;

    int cmax = (q0 + 15) >> 5;
    for (int c = 0; c <= cmax; ++c) {
        __syncthreads();
#pragma unroll
        for (int u = 0; u < 16; ++u) {
            int e = t + u * 256;
            int row = e >> 7, d = e & 127;
            int pos = c * 32 + row;
            float x  = k[(size_t)pos * 1024 + kvh * 128 + d];
            float x2 = k[(size_t)pos * 1024 + kvh * 128 + (d ^ 64)];
            float cs = cosb[pos * 64 + (d & 63)];
            float sn = sinb[pos * 64 + (d & 63)];
            float rot = (d < 64) ? -x2 : x2;
            krs[row][d] = x * cs + rot * sn;
            vs[row][d]  = v[(size_t)pos * 1024 + kvh * 128 + d];
        }
        __syncthreads();

        float s0 = 0.f, s1 = 0.f;
#pragma unroll
        for (int d = 0; d < 128; d += 4) {
            float4 a  = *(const float4*)(&qrs[i][d]);
            float4 b0 = *(const float4*)(&krs[jj][d]);
            float4 b1 = *(const float4*)(&krs[jj + 16][d]);
            s0 += a.x * b0.x + a.y * b0.y + a.z * b0.z + a.w * b0.w;
            s1 += a.x * b1.x + a.y * b1.y + a.z * b1.z + a.w * b1.w;
        }

        unsigned long long mw = mask[((size_t)h * 1024 + qrow) * 16 + (c >> 1)];
        unsigned int mb = (unsigned int)(mw >> ((c & 1) * 32));
        int j0 = c * 32 + jj, j1 = j0 + 16;
        bool ok0 = (j0 <= qrow) && ((mb >> jj) & 1u);
        bool ok1 = (j1 <= qrow) && ((mb >> (jj + 16)) & 1u);

        float cm = fmaxf(ok0 ? s0 : -3.0e38f, ok1 ? s1 : -3.0e38f);
        cm = fmaxf(cm, __shfl_xor(cm, 1));
        cm = fmaxf(cm, __shfl_xor(cm, 2));
        cm = fmaxf(cm, __shfl_xor(cm, 4));
        cm = fmaxf(cm, __shfl_xor(cm, 8));
        float m_new = fmaxf(m_run, cm);
        float sf = __expf(m_run - m_new);   // finite sentinels: no NaN path
        float p0 = ok0 ? __expf(s0 - m_new) : 0.f;
        float p1 = ok1 ? __expf(s1 - m_new) : 0.f;
        float ps = p0 + p1;
        ps += __shfl_xor(ps, 1);
        ps += __shfl_xor(ps, 2);
        ps += __shfl_xor(ps, 4);
        ps += __shfl_xor(ps, 8);
        l_run = l_run * sf + ps;
        m_run = m_new;

#pragma unroll
        for (int u = 0; u < 8; ++u) o[u] *= sf;
#pragma unroll 8
        for (int j = 0; j < 32; ++j) {
            float pj = (j < 16) ? __shfl(p0, rbase + j) : __shfl(p1, rbase + (j - 16));
            float4 v0 = *(const float4*)(&vs[j][jj * 8]);
            float4 v1 = *(const float4*)(&vs[j][jj * 8 + 4]);
            o[0] = fmaf(pj, v0.x, o[0]); o[1] = fmaf(pj, v0.y, o[1]);
            o[2] = fmaf(pj, v0.z, o[2]); o[3] = fmaf(pj, v0.w, o[3]);
            o[4] = fmaf(pj, v1.x, o[4]); o[5] = fmaf(pj, v1.y, o[5]);
            o[6] = fmaf(pj, v1.z, o[6]); o[7] = fmaf(pj, v1.w, o[7]);
        }
    }

    float inv_l = 1.0f / l_run;
    float4 o0 = make_float4(o[0] * inv_l, o[1] * inv_l, o[2] * inv_l, o[3] * inv_l);
    float4 o1 = make_float4(o[4] * inv_l, o[5] * inv_l, o[6] * inv_l, o[7] * inv_l);
    *(float4*)(attn + (size_t)qrow * 4096 + h * 128 + jj * 8)     = o0;
    *(float4*)(attn + (size_t)qrow * 4096 + h * 128 + jj * 8 + 4) = o1;
}

extern "C" void kernel_launch(void* const* d_in, const int* in_sizes, int n_in,
                              void* d_out, int out_size, void* d_ws, size_t ws_size,
                              hipStream_t stream)
{
    (void)in_sizes; (void)n_in; (void)out_size; (void)ws_size;
    const float* hs   = (const float*)d_in[0];
    const float* wq   = (const float*)d_in[1];
    const float* wk   = (const float*)d_in[2];
    const float* wv   = (const float*)d_in[3];
    const float* wo   = (const float*)d_in[4];
    const float* mixq = (const float*)d_in[5];
    const float* mixk = (const float*)d_in[6];
    const float* qpos = (const float*)d_in[7];
    const float* kpos = (const float*)d_in[8];
    float* out = (float*)d_out;

    // workspace layout (~80.5 MB total)
    float* ws   = (float*)d_ws;
    float* qb   = ws;                     // 1024*4096
    float* kb   = qb + 4194304;           // 1024*1024
    float* vb   = kb + 1048576;           // 1024*1024
    float* attn = vb + 1048576;           // 1024*4096
    float* pq   = attn + 4194304;         // 32*1024*128
    float* pk   = pq + 4194304;           // 32*1024*128
    float* lrq  = pk + 4194304;           // 1024*32
    float* lrk  = lrq + 32768;            // 1024*32
    float* cosb = lrk + 32768;            // 1024*64
    float* sinb = cosb + 65536;           // 1024*64
    unsigned long long* mask = (unsigned long long*)(sinb + 65536); // 32*1024*16

    hipLaunchKernelGGL(rope_tables_kernel, dim3(1024), dim3(64), 0, stream, cosb, sinb);
    hipLaunchKernelGGL(gemm_qkv_kernel, dim3(48, 8), dim3(256), 0, stream,
                       hs, wq, wk, wv, qb, kb, vb);
    hipLaunchKernelGGL(lr_kernel, dim3(1024), dim3(256), 0, stream,
                       hs, mixq, mixk, lrq, lrk);
    hipLaunchKernelGGL(ppos_kernel, dim3(32, 1024), dim3(128), 0, stream, lrq, qpos, pq);
    hipLaunchKernelGGL(ppos_kernel, dim3(32, 1024), dim3(128), 0, stream, lrk, kpos, pk);
    hipLaunchKernelGGL(draft_select_kernel, dim3(64, 32), dim3(256), 0, stream, pq, pk, mask);
    hipLaunchKernelGGL(attn_kernel, dim3(64, 32), dim3(256), 0, stream,
                       qb, kb, vb, cosb, sinb, mask, attn);
    hipLaunchKernelGGL(gemm_plain_kernel, dim3(32, 8), dim3(256), 0, stream,
                       attn, wo, out, 4096, 4096);
}

// Round 2
// 1408.631 us; speedup vs baseline: 1.7946x; 1.7946x over previous
//
#include <hip/hip_runtime.h>
#include <hip/hip_bf16.h>
#include <math.h>

// Decoder_62234076119175 — round 2: bf16 MFMA for qkv + wo GEMMs.
// Draft/top-k path stays f32 end-to-end (discrete selection must match numpy).

typedef unsigned short u16;
using bf16x8 = __attribute__((ext_vector_type(8))) short;
using f32x4  = __attribute__((ext_vector_type(4))) float;

#define NEGBIG -1e30f

__device__ __forceinline__ unsigned int fkey(float f) {
    unsigned int u = __float_as_uint(f);
    return (u & 0x80000000u) ? ~u : (u | 0x80000000u);
}

__device__ __forceinline__ u16 f2b(float f) {
    union { float f; unsigned u; } x; x.f = f;
    unsigned r = x.u + 0x7fffu + ((x.u >> 16) & 1u);  // RNE
    return (u16)(r >> 16);
}

__device__ __forceinline__ void gl_lds16(const u16* g, u16* l) {
    __builtin_amdgcn_global_load_lds(
        (__attribute__((address_space(1))) void*)(g),
        (__attribute__((address_space(3))) void*)(l), 16, 0, 0);
}

// ---------------- RoPE tables ----------------
__global__ void rope_tables_kernel(float* __restrict__ cosb, float* __restrict__ sinb) {
    int t = blockIdx.x;
    int i = threadIdx.x; // 0..63
    double inv = pow(10000.0, -((double)(2 * i)) / 128.0);
    double ang = (double)t * inv;
    cosb[t * 64 + i] = (float)cos(ang);
    sinb[t * 64 + i] = (float)sin(ang);
}

// ---------------- f32 -> bf16 elementwise (hs) ----------------
__global__ __launch_bounds__(256) void conv_bf16_kernel(const float* __restrict__ in, u16* __restrict__ out) {
    int i = blockIdx.x * 256 + threadIdx.x;
    float4 v = ((const float4*)in)[i];
    u16 o[4] = {f2b(v.x), f2b(v.y), f2b(v.z), f2b(v.w)};
    ((uint2*)out)[i] = *(const uint2*)o;
}

// ---------------- f32 [K][N] -> bf16 [N][K] transpose ----------------
__global__ __launch_bounds__(256) void transpose_bf16_kernel(
    const float* __restrict__ in, u16* __restrict__ out, int Kdim, int N)
{
    __shared__ u16 tile[64][66];
    int n0 = blockIdx.x * 64, k0 = blockIdx.y * 64;
    int t = threadIdx.x;
#pragma unroll
    for (int u = 0; u < 16; ++u) {
        int e = u * 256 + t; int r = e >> 6, c = e & 63;
        tile[r][c] = f2b(in[(size_t)(k0 + r) * N + n0 + c]);
    }
    __syncthreads();
#pragma unroll
    for (int u = 0; u < 16; ++u) {
        int e = u * 256 + t; int r = e >> 6, c = e & 63;  // r: n-local, c: k-local
        out[(size_t)(n0 + r) * Kdim + k0 + c] = tile[c][r];
    }
}

// ---------------- bf16 MFMA GEMM: C[M][N] f32 = A[M][K] x BT[N][K] ----------
// m97 structure: 128x128 tile, 4 waves (2x2), BK=32, global_load_lds w=16.
__device__ __forceinline__ void gemm_bf16_tile(
    const u16* __restrict__ A, const u16* __restrict__ BT, float* __restrict__ C,
    int Kdim, int Ncols, int bm, int bn)
{
    __shared__ u16 As[128 * 32];
    __shared__ u16 Bs[128 * 32];
    const int t = threadIdx.x;
    const int wave = t >> 6, lane = t & 63;
    const int wr = wave >> 1, wc = wave & 1;
    const int fr = lane & 15, fq = lane >> 4;

    f32x4 acc[4][4];
#pragma unroll
    for (int m = 0; m < 4; ++m)
#pragma unroll
        for (int n = 0; n < 4; ++n) acc[m][n] = 0.f;

    // staging: chunk = 1024B = 16 rows x 32 bf16; wave w stages chunks 2w, 2w+1
    const int srow = 32 * wave + (lane >> 2);
    const int skc = (lane & 3) * 8;
    const u16* aS = A  + ((size_t)(bm * 128) + srow) * Kdim + skc;
    const u16* bS = BT + ((size_t)(bn * 128) + srow) * Kdim + skc;
    u16* aD0 = As + 1024 * wave;  u16* aD1 = aD0 + 512;
    u16* bD0 = Bs + 1024 * wave;  u16* bD1 = bD0 + 512;

    const int aoff = (wr * 64 + fr) * 32 + fq * 8;   // + m*512
    const int boff = (wc * 64 + fr) * 32 + fq * 8;   // + n*512

    for (int k0 = 0; k0 < Kdim; k0 += 32) {
        __syncthreads();
        gl_lds16(aS + k0, aD0);
        gl_lds16(aS + (size_t)16 * Kdim + k0, aD1);
        gl_lds16(bS + k0, bD0);
        gl_lds16(bS + (size_t)16 * Kdim + k0, bD1);
        __syncthreads();

        bf16x8 af[4], bfr[4];
#pragma unroll
        for (int m = 0; m < 4; ++m) af[m] = *(const bf16x8*)(As + aoff + m * 512);
#pragma unroll
        for (int n = 0; n < 4; ++n) bfr[n] = *(const bf16x8*)(Bs + boff + n * 512);
#pragma unroll
        for (int m = 0; m < 4; ++m)
#pragma unroll
            for (int n = 0; n < 4; ++n)
                acc[m][n] = __builtin_amdgcn_mfma_f32_16x16x32_bf16(af[m], bfr[n], acc[m][n], 0, 0, 0);
    }

    float* Cb = C + (size_t)(bm * 128 + wr * 64 + fq * 4) * Ncols + bn * 128 + wc * 64 + fr;
#pragma unroll
    for (int m = 0; m < 4; ++m)
#pragma unroll
        for (int j = 0; j < 4; ++j)
#pragma unroll
            for (int n = 0; n < 4; ++n)
                Cb[(size_t)(m * 16 + j) * Ncols + n * 16] = acc[m][n][j];
}

__global__ __launch_bounds__(256) void gemm_qkv_bf16_kernel(
    const u16* __restrict__ hs_bf, const u16* __restrict__ wqT,
    const u16* __restrict__ wkT, const u16* __restrict__ wvT,
    float* __restrict__ q, float* __restrict__ k, float* __restrict__ v)
{
    int bn = blockIdx.x, bm = blockIdx.y;
    const u16* Bsel; float* Csel; int Ncols;
    if (bn < 32)      { Bsel = wqT; Csel = q; Ncols = 4096; }
    else if (bn < 40) { Bsel = wkT; Csel = k; Ncols = 1024; bn -= 32; }
    else              { Bsel = wvT; Csel = v; Ncols = 1024; bn -= 40; }
    gemm_bf16_tile(hs_bf, Bsel, Csel, 4096, Ncols, bm, bn);
}

__global__ __launch_bounds__(256) void gemm_wo_bf16_kernel(
    const u16* __restrict__ attn_bf, const u16* __restrict__ woT, float* __restrict__ out)
{
    gemm_bf16_tile(attn_bf, woT, out, 4096, 4096, blockIdx.y, blockIdx.x);
}

// ---------------- lrq/lrk = hs @ mixq / mixk (f32, exact path) -------------
__global__ __launch_bounds__(256) void lr_kernel(
    const float* __restrict__ hs, const float* __restrict__ mixq, const float* __restrict__ mixk,
    float* __restrict__ lrq, float* __restrict__ lrk)
{
    __shared__ float row[4096];
    __shared__ float part[2][32][4];
    int m = blockIdx.x, t = threadIdx.x;
#pragma unroll
    for (int u = 0; u < 4; ++u)
        ((float4*)row)[t + u * 256] = ((const float4*)(hs + (size_t)m * 4096))[t + u * 256];
    __syncthreads();
    int r = t & 31, which = (t >> 5) & 1, quarter = t >> 6;
    const float* mix = which ? mixk : mixq;
    float acc = 0.f;
    int kbase = quarter * 1024;
#pragma unroll 8
    for (int kk = 0; kk < 1024; ++kk)
        acc = fmaf(row[kbase + kk], mix[(size_t)(kbase + kk) * 32 + r], acc);
    part[which][r][quarter] = acc;
    __syncthreads();
    if (t < 64) {
        int r2 = t & 31, w2 = t >> 5;
        float s = part[w2][r2][0] + part[w2][r2][1] + part[w2][r2][2] + part[w2][r2][3];
        (w2 ? lrk : lrq)[(size_t)m * 32 + r2] = s;
    }
}

// ---------------- pq/pk[h][m][d] = sum_r lr[m][r] * pos[m][h][r][d] --------
__global__ __launch_bounds__(128) void ppos_kernel(
    const float* __restrict__ lr, const float* __restrict__ pos, float* __restrict__ out)
{
    int h = blockIdx.x, m = blockIdx.y, d = threadIdx.x;
    __shared__ float lrs[32];
    if (d < 32) lrs[d] = lr[(size_t)m * 32 + d];
    __syncthreads();
    const float* base = pos + ((size_t)(m * 32 + h) * 32) * 128 + d;
    float acc = 0.f;
#pragma unroll
    for (int r = 0; r < 32; ++r)
        acc = fmaf(lrs[r], base[(size_t)r * 128], acc);
    out[((size_t)h * 1024 + m) * 128 + d] = acc;
}

// ---------------- draft score + exact top-512 radix select -----------------
__global__ __launch_bounds__(256) void draft_select_kernel(
    const float* __restrict__ pq, const float* __restrict__ pk,
    unsigned long long* __restrict__ mask)
{
    int qt = blockIdx.x, h = blockIdx.y;
    int q0 = qt * 16;
    int t = threadIdx.x;
    __shared__ float pqs[16][132];
    __shared__ float pks[32][132];

    const float* pqh = pq + ((size_t)h * 1024 + q0) * 128;
    const float* pkh = pk + (size_t)h * 1024 * 128;

#pragma unroll
    for (int u = 0; u < 2; ++u) {
        int f4 = t + u * 256;
        int row = f4 >> 5, dg = (f4 & 31) * 4;
        *(float4*)(&pqs[row][dg]) = *(const float4*)(pqh + (size_t)row * 128 + dg);
    }

    int i = t >> 4, jj = t & 15;
    int qrow = q0 + i;
    unsigned int vals[64];

#pragma unroll
    for (int c = 0; c < 32; ++c) {
        __syncthreads();
#pragma unroll
        for (int u = 0; u < 4; ++u) {
            int f4 = t + u * 256;
            int row = f4 >> 5, dg = (f4 & 31) * 4;
            *(float4*)(&pks[row][dg]) = *(const float4*)(pkh + (size_t)(c * 32 + row) * 128 + dg);
        }
        __syncthreads();
        float s0 = 0.f, s1 = 0.f;
#pragma unroll
        for (int d = 0; d < 128; d += 4) {
            float4 a  = *(const float4*)(&pqs[i][d]);
            float4 b0 = *(const float4*)(&pks[jj][d]);
            float4 b1 = *(const float4*)(&pks[jj + 16][d]);
            s0 += a.x * b0.x + a.y * b0.y + a.z * b0.z + a.w * b0.w;
            s1 += a.x * b1.x + a.y * b1.y + a.z * b1.z + a.w * b1.w;
        }
        int j0 = c * 32 + jj, j1 = j0 + 16;
        vals[2 * c]     = fkey(j0 <= qrow ? s0 : NEGBIG);
        vals[2 * c + 1] = fkey(j1 <= qrow ? s1 : NEGBIG);
    }

    unsigned int p = 0u;
    int kth = 512;
    for (int b = 31; b >= 0; --b) {
        unsigned int bit = 1u << b;
        unsigned int himask = (b == 31) ? 0u : (0xFFFFFFFFu << (b + 1));
        int cnt = 0;
#pragma unroll
        for (int n = 0; n < 64; ++n)
            cnt += (int)((((vals[n] ^ p) & himask) == 0u) && ((vals[n] & bit) != 0u));
        cnt += __shfl_xor(cnt, 1);
        cnt += __shfl_xor(cnt, 2);
        cnt += __shfl_xor(cnt, 4);
        cnt += __shfl_xor(cnt, 8);
        if (cnt >= kth) p |= bit; else kth -= cnt;
    }

    unsigned long long wpart[16];
#pragma unroll
    for (int w = 0; w < 16; ++w) wpart[w] = 0ull;
#pragma unroll
    for (int n = 0; n < 64; ++n) {
        int w = n >> 2;
        int bpos = jj + ((n & 3) << 4);
        wpart[w] |= ((unsigned long long)(vals[n] >= p)) << bpos;
    }
#pragma unroll
    for (int s = 1; s < 16; s <<= 1) {
#pragma unroll
        for (int w = 0; w < 16; ++w)
            wpart[w] |= __shfl_xor(wpart[w], s);
    }
    mask[((size_t)h * 1024 + qrow) * 16 + jj] = wpart[jj];
}

// ---------------- masked flash attention (f32), bf16 output ----------------
__global__ __launch_bounds__(256) void attn_kernel(
    const float* __restrict__ q, const float* __restrict__ k, const float* __restrict__ v,
    const float* __restrict__ cosb, const float* __restrict__ sinb,
    const unsigned long long* __restrict__ mask, u16* __restrict__ attn)
{
    int qt = blockIdx.x, h = blockIdx.y;
    int q0 = qt * 16;
    int kvh = h >> 2;
    int t = threadIdx.x;
    __shared__ float qrs[16][132];
    __shared__ float krs[32][132];
    __shared__ float vs[32][132];

#pragma unroll
    for (int u = 0; u < 8; ++u) {
        int e = t + u * 256;
        int row = e >> 7, d = e & 127;
        int pos = q0 + row;
        float x  = q[(size_t)pos * 4096 + h * 128 + d];
        float x2 = q[(size_t)pos * 4096 + h * 128 + (d ^ 64)];
        float cs = cosb[pos * 64 + (d & 63)];
        float sn = sinb[pos * 64 + (d & 63)];
        float rot = (d < 64) ? -x2 : x2;
        qrs[row][d] = (x * cs + rot * sn) * 0.08838834764831845f;
    }

    int i = t >> 4, jj = t & 15;
    int rbase = (t & 63) & ~15;
    int qrow = q0 + i;
    float m_run = -3.0e38f, l_run = 0.f;
    float o[8];
#pragma unroll
    for (int u = 0; u < 8; ++u) o[u] = 0.f;

    int cmax = (q0 + 15) >> 5;
    for (int c = 0; c <= cmax; ++c) {
        __syncthreads();
#pragma unroll
        for (int u = 0; u < 16; ++u) {
            int e = t + u * 256;
            int row = e >> 7, d = e & 127;
            int pos = c * 32 + row;
            float x  = k[(size_t)pos * 1024 + kvh * 128 + d];
            float x2 = k[(size_t)pos * 1024 + kvh * 128 + (d ^ 64)];
            float cs = cosb[pos * 64 + (d & 63)];
            float sn = sinb[pos * 64 + (d & 63)];
            float rot = (d < 64) ? -x2 : x2;
            krs[row][d] = x * cs + rot * sn;
            vs[row][d]  = v[(size_t)pos * 1024 + kvh * 128 + d];
        }
        __syncthreads();

        float s0 = 0.f, s1 = 0.f;
#pragma unroll
        for (int d = 0; d < 128; d += 4) {
            float4 a  = *(const float4*)(&qrs[i][d]);
            float4 b0 = *(const float4*)(&krs[jj][d]);
            float4 b1 = *(const float4*)(&krs[jj + 16][d]);
            s0 += a.x * b0.x + a.y * b0.y + a.z * b0.z + a.w * b0.w;
            s1 += a.x * b1.x + a.y * b1.y + a.z * b1.z + a.w * b1.w;
        }

        unsigned long long mw = mask[((size_t)h * 1024 + qrow) * 16 + (c >> 1)];
        unsigned int mb = (unsigned int)(mw >> ((c & 1) * 32));
        int j0 = c * 32 + jj, j1 = j0 + 16;
        bool ok0 = (j0 <= qrow) && ((mb >> jj) & 1u);
        bool ok1 = (j1 <= qrow) && ((mb >> (jj + 16)) & 1u);

        float cm = fmaxf(ok0 ? s0 : -3.0e38f, ok1 ? s1 : -3.0e38f);
        cm = fmaxf(cm, __shfl_xor(cm, 1));
        cm = fmaxf(cm, __shfl_xor(cm, 2));
        cm = fmaxf(cm, __shfl_xor(cm, 4));
        cm = fmaxf(cm, __shfl_xor(cm, 8));
        float m_new = fmaxf(m_run, cm);
        float sf = __expf(m_run - m_new);
        float p0 = ok0 ? __expf(s0 - m_new) : 0.f;
        float p1 = ok1 ? __expf(s1 - m_new) : 0.f;
        float ps = p0 + p1;
        ps += __shfl_xor(ps, 1);
        ps += __shfl_xor(ps, 2);
        ps += __shfl_xor(ps, 4);
        ps += __shfl_xor(ps, 8);
        l_run = l_run * sf + ps;
        m_run = m_new;

#pragma unroll
        for (int u = 0; u < 8; ++u) o[u] *= sf;
#pragma unroll 8
        for (int j = 0; j < 32; ++j) {
            float pj = (j < 16) ? __shfl(p0, rbase + j) : __shfl(p1, rbase + (j - 16));
            float4 v0 = *(const float4*)(&vs[j][jj * 8]);
            float4 v1 = *(const float4*)(&vs[j][jj * 8 + 4]);
            o[0] = fmaf(pj, v0.x, o[0]); o[1] = fmaf(pj, v0.y, o[1]);
            o[2] = fmaf(pj, v0.z, o[2]); o[3] = fmaf(pj, v0.w, o[3]);
            o[4] = fmaf(pj, v1.x, o[4]); o[5] = fmaf(pj, v1.y, o[5]);
            o[6] = fmaf(pj, v1.z, o[6]); o[7] = fmaf(pj, v1.w, o[7]);
        }
    }

    float il = 1.0f / l_run;
    uint4 w;
    w.x = (unsigned)f2b(o[0] * il) | ((unsigned)f2b(o[1] * il) << 16);
    w.y = (unsigned)f2b(o[2] * il) | ((unsigned)f2b(o[3] * il) << 16);
    w.z = (unsigned)f2b(o[4] * il) | ((unsigned)f2b(o[5] * il) << 16);
    w.w = (unsigned)f2b(o[6] * il) | ((unsigned)f2b(o[7] * il) << 16);
    *(uint4*)(attn + (size_t)qrow * 4096 + h * 128 + jj * 8) = w;
}

extern "C" void kernel_launch(void* const* d_in, const int* in_sizes, int n_in,
                              void* d_out, int out_size, void* d_ws, size_t ws_size,
                              hipStream_t stream)
{
    (void)in_sizes; (void)n_in; (void)out_size; (void)ws_size;
    const float* hs   = (const float*)d_in[0];
    const float* wq   = (const float*)d_in[1];
    const float* wk   = (const float*)d_in[2];
    const float* wv   = (const float*)d_in[3];
    const float* wo   = (const float*)d_in[4];
    const float* mixq = (const float*)d_in[5];
    const float* mixk = (const float*)d_in[6];
    const float* qpos = (const float*)d_in[7];
    const float* kpos = (const float*)d_in[8];
    float* out = (float*)d_out;

    // workspace layout (time-aliased; high-water ~89 MB)
    float* ws   = (float*)d_ws;
    float* qb   = ws;                     // 4M f32
    float* kb   = qb + 4194304;           // 1M
    float* vb   = kb + 1048576;           // 1M
    float* pq   = vb + 1048576;           // 4M  } R1: also wqT (qkv phase) and
    float* pk   = pq + 4194304;           // 4M  }     woT (output phase), 32MB
    float* lrq  = pk + 4194304;
    float* lrk  = lrq + 32768;
    float* cosb = lrk + 32768;
    float* sinb = cosb + 65536;
    unsigned long long* mask = (unsigned long long*)(sinb + 65536); // 512K u64
    u16* hs_bf = (u16*)(ws + 14876672 + 1048576);  // 4M u16 (also attn_bf later)
    u16* wkT   = hs_bf + 4194304;                  // 4M u16
    u16* wvT   = wkT + 4194304;                    // 4M u16
    u16* wqT   = (u16*)pq;                         // 16M u16 (alias R1)
    u16* woT   = (u16*)pq;                         // 16M u16 (alias R1, later)
    u16* attn_bf = hs_bf;                          // alias (hs_bf dead by then)

    hipLaunchKernelGGL(rope_tables_kernel, dim3(1024), dim3(64), 0, stream, cosb, sinb);
    hipLaunchKernelGGL(conv_bf16_kernel, dim3(4096), dim3(256), 0, stream, hs, hs_bf);
    hipLaunchKernelGGL(transpose_bf16_kernel, dim3(64, 64), dim3(256), 0, stream, wq, wqT, 4096, 4096);
    hipLaunchKernelGGL(transpose_bf16_kernel, dim3(16, 64), dim3(256), 0, stream, wk, wkT, 4096, 1024);
    hipLaunchKernelGGL(transpose_bf16_kernel, dim3(16, 64), dim3(256), 0, stream, wv, wvT, 4096, 1024);
    hipLaunchKernelGGL(gemm_qkv_bf16_kernel, dim3(48, 8), dim3(256), 0, stream,
                       hs_bf, wqT, wkT, wvT, qb, kb, vb);
    hipLaunchKernelGGL(lr_kernel, dim3(1024), dim3(256), 0, stream, hs, mixq, mixk, lrq, lrk);
    hipLaunchKernelGGL(ppos_kernel, dim3(32, 1024), dim3(128), 0, stream, lrq, qpos, pq);
    hipLaunchKernelGGL(ppos_kernel, dim3(32, 1024), dim3(128), 0, stream, lrk, kpos, pk);
    hipLaunchKernelGGL(draft_select_kernel, dim3(64, 32), dim3(256), 0, stream, pq, pk, mask);
    hipLaunchKernelGGL(attn_kernel, dim3(64, 32), dim3(256), 0, stream,
                       qb, kb, vb, cosb, sinb, mask, attn_bf);
    hipLaunchKernelGGL(transpose_bf16_kernel, dim3(64, 64), dim3(256), 0, stream, wo, woT, 4096, 4096);
    hipLaunchKernelGGL(gemm_wo_bf16_kernel, dim3(32, 8), dim3(256), 0, stream,
                       attn_bf, woT, out);
}

// Round 4
// 949.798 us; speedup vs baseline: 2.6615x; 1.4831x over previous
//
#include <hip/hip_runtime.h>
#include <hip/hip_bf16.h>
#include <math.h>

// Decoder_62234076119175 — round 4: MFMA flash attention, fixed P^T shuffle.
// Draft/top-k path stays f32 end-to-end (discrete selection must match numpy).

typedef unsigned short u16;
using bf16x8 = __attribute__((ext_vector_type(8))) short;
using f32x4  = __attribute__((ext_vector_type(4))) float;

#define NEGBIG -1e30f

__device__ __forceinline__ unsigned int fkey(float f) {
    unsigned int u = __float_as_uint(f);
    return (u & 0x80000000u) ? ~u : (u | 0x80000000u);
}

__device__ __forceinline__ u16 f2b(float f) {
    union { float f; unsigned u; } x; x.f = f;
    unsigned r = x.u + 0x7fffu + ((x.u >> 16) & 1u);  // RNE
    return (u16)(r >> 16);
}

__device__ __forceinline__ void gl_lds16(const u16* g, u16* l) {
    __builtin_amdgcn_global_load_lds(
        (__attribute__((address_space(1))) void*)(g),
        (__attribute__((address_space(3))) void*)(l), 16, 0, 0);
}

// ---------------- RoPE tables ----------------
__global__ void rope_tables_kernel(float* __restrict__ cosb, float* __restrict__ sinb) {
    int t = blockIdx.x;
    int i = threadIdx.x; // 0..63
    double inv = pow(10000.0, -((double)(2 * i)) / 128.0);
    double ang = (double)t * inv;
    cosb[t * 64 + i] = (float)cos(ang);
    sinb[t * 64 + i] = (float)sin(ang);
}

// ---------------- f32 -> bf16 elementwise (hs) ----------------
__global__ __launch_bounds__(256) void conv_bf16_kernel(const float* __restrict__ in, u16* __restrict__ out) {
    int i = blockIdx.x * 256 + threadIdx.x;
    float4 v = ((const float4*)in)[i];
    u16 o[4] = {f2b(v.x), f2b(v.y), f2b(v.z), f2b(v.w)};
    ((uint2*)out)[i] = *(const uint2*)o;
}

// ---------------- f32 [K][N] -> bf16 [N][K] transpose ----------------
__global__ __launch_bounds__(256) void transpose_bf16_kernel(
    const float* __restrict__ in, u16* __restrict__ out, int Kdim, int N)
{
    __shared__ u16 tile[64][66];
    int n0 = blockIdx.x * 64, k0 = blockIdx.y * 64;
    int t = threadIdx.x;
#pragma unroll
    for (int u = 0; u < 16; ++u) {
        int e = u * 256 + t; int r = e >> 6, c = e & 63;
        tile[r][c] = f2b(in[(size_t)(k0 + r) * N + n0 + c]);
    }
    __syncthreads();
#pragma unroll
    for (int u = 0; u < 16; ++u) {
        int e = u * 256 + t; int r = e >> 6, c = e & 63;
        out[(size_t)(n0 + r) * Kdim + k0 + c] = tile[c][r];
    }
}

// ---------------- RoPE apply + scale + bf16 pack: [s][W] -> [h][s][128] ----
__global__ __launch_bounds__(128) void rope_pack_kernel(
    const float* __restrict__ src, int W, const float* __restrict__ cosb,
    const float* __restrict__ sinb, u16* __restrict__ dst, float scale)
{
    int s = blockIdx.x, h = blockIdx.y, d = threadIdx.x;
    float x  = src[(size_t)s * W + h * 128 + d];
    float x2 = src[(size_t)s * W + h * 128 + (d ^ 64)];
    float cs = cosb[s * 64 + (d & 63)];
    float sn = sinb[s * 64 + (d & 63)];
    float rot = (d < 64) ? -x2 : x2;
    dst[((size_t)h * 1024 + s) * 128 + d] = f2b((x * cs + rot * sn) * scale);
}

// ---------------- bf16 MFMA GEMM: C[M][N] f32 = A[M][K] x BT[N][K] ----------
__device__ __forceinline__ void gemm_bf16_tile(
    const u16* __restrict__ A, const u16* __restrict__ BT, float* __restrict__ C,
    int Kdim, int Ncols, int bm, int bn)
{
    __shared__ u16 As[128 * 32];
    __shared__ u16 Bs[128 * 32];
    const int t = threadIdx.x;
    const int wave = t >> 6, lane = t & 63;
    const int wr = wave >> 1, wc = wave & 1;
    const int fr = lane & 15, fq = lane >> 4;

    f32x4 acc[4][4];
#pragma unroll
    for (int m = 0; m < 4; ++m)
#pragma unroll
        for (int n = 0; n < 4; ++n) acc[m][n] = 0.f;

    const int srow = 32 * wave + (lane >> 2);
    const int skc = (lane & 3) * 8;
    const u16* aS = A  + ((size_t)(bm * 128) + srow) * Kdim + skc;
    const u16* bS = BT + ((size_t)(bn * 128) + srow) * Kdim + skc;
    u16* aD0 = As + 1024 * wave;  u16* aD1 = aD0 + 512;
    u16* bD0 = Bs + 1024 * wave;  u16* bD1 = bD0 + 512;

    const int aoff = (wr * 64 + fr) * 32 + fq * 8;
    const int boff = (wc * 64 + fr) * 32 + fq * 8;

    for (int k0 = 0; k0 < Kdim; k0 += 32) {
        __syncthreads();
        gl_lds16(aS + k0, aD0);
        gl_lds16(aS + (size_t)16 * Kdim + k0, aD1);
        gl_lds16(bS + k0, bD0);
        gl_lds16(bS + (size_t)16 * Kdim + k0, bD1);
        __syncthreads();

        bf16x8 af[4], bfr[4];
#pragma unroll
        for (int m = 0; m < 4; ++m) af[m] = *(const bf16x8*)(As + aoff + m * 512);
#pragma unroll
        for (int n = 0; n < 4; ++n) bfr[n] = *(const bf16x8*)(Bs + boff + n * 512);
#pragma unroll
        for (int m = 0; m < 4; ++m)
#pragma unroll
            for (int n = 0; n < 4; ++n)
                acc[m][n] = __builtin_amdgcn_mfma_f32_16x16x32_bf16(af[m], bfr[n], acc[m][n], 0, 0, 0);
    }

    float* Cb = C + (size_t)(bm * 128 + wr * 64 + fq * 4) * Ncols + bn * 128 + wc * 64 + fr;
#pragma unroll
    for (int m = 0; m < 4; ++m)
#pragma unroll
        for (int j = 0; j < 4; ++j)
#pragma unroll
            for (int n = 0; n < 4; ++n)
                Cb[(size_t)(m * 16 + j) * Ncols + n * 16] = acc[m][n][j];
}

__global__ __launch_bounds__(256) void gemm_qkv_bf16_kernel(
    const u16* __restrict__ hs_bf, const u16* __restrict__ wqT,
    const u16* __restrict__ wkT, const u16* __restrict__ wvT,
    float* __restrict__ q, float* __restrict__ k, float* __restrict__ v)
{
    int bn = blockIdx.x, bm = blockIdx.y;
    const u16* Bsel; float* Csel; int Ncols;
    if (bn < 32)      { Bsel = wqT; Csel = q; Ncols = 4096; }
    else if (bn < 40) { Bsel = wkT; Csel = k; Ncols = 1024; bn -= 32; }
    else              { Bsel = wvT; Csel = v; Ncols = 1024; bn -= 40; }
    gemm_bf16_tile(hs_bf, Bsel, Csel, 4096, Ncols, bm, bn);
}

__global__ __launch_bounds__(256) void gemm_wo_bf16_kernel(
    const u16* __restrict__ attn_bf, const u16* __restrict__ woT, float* __restrict__ out)
{
    gemm_bf16_tile(attn_bf, woT, out, 4096, 4096, blockIdx.y, blockIdx.x);
}

// ---------------- lrq/lrk = hs @ mixq / mixk (f32, exact path) -------------
__global__ __launch_bounds__(256) void lr_kernel(
    const float* __restrict__ hs, const float* __restrict__ mixq, const float* __restrict__ mixk,
    float* __restrict__ lrq, float* __restrict__ lrk)
{
    __shared__ float row[4096];
    __shared__ float part[2][32][4];
    int m = blockIdx.x, t = threadIdx.x;
#pragma unroll
    for (int u = 0; u < 4; ++u)
        ((float4*)row)[t + u * 256] = ((const float4*)(hs + (size_t)m * 4096))[t + u * 256];
    __syncthreads();
    int r = t & 31, which = (t >> 5) & 1, quarter = t >> 6;
    const float* mix = which ? mixk : mixq;
    float acc = 0.f;
    int kbase = quarter * 1024;
#pragma unroll 8
    for (int kk = 0; kk < 1024; ++kk)
        acc = fmaf(row[kbase + kk], mix[(size_t)(kbase + kk) * 32 + r], acc);
    part[which][r][quarter] = acc;
    __syncthreads();
    if (t < 64) {
        int r2 = t & 31, w2 = t >> 5;
        float s = part[w2][r2][0] + part[w2][r2][1] + part[w2][r2][2] + part[w2][r2][3];
        (w2 ? lrk : lrq)[(size_t)m * 32 + r2] = s;
    }
}

// ---------------- pq/pk[h][m][d] = sum_r lr[m][r] * pos[m][h][r][d] --------
__global__ __launch_bounds__(128) void ppos_kernel(
    const float* __restrict__ lr, const float* __restrict__ pos, float* __restrict__ out)
{
    int h = blockIdx.x, m = blockIdx.y, d = threadIdx.x;
    __shared__ float lrs[32];
    if (d < 32) lrs[d] = lr[(size_t)m * 32 + d];
    __syncthreads();
    const float* base = pos + ((size_t)(m * 32 + h) * 32) * 128 + d;
    float acc = 0.f;
#pragma unroll
    for (int r = 0; r < 32; ++r)
        acc = fmaf(lrs[r], base[(size_t)r * 128], acc);
    out[((size_t)h * 1024 + m) * 128 + d] = acc;
}

// ---------------- draft score + exact top-512 radix select -----------------
__global__ __launch_bounds__(256) void draft_select_kernel(
    const float* __restrict__ pq, const float* __restrict__ pk,
    unsigned long long* __restrict__ mask)
{
    int qt = blockIdx.x, h = blockIdx.y;
    int q0 = qt * 16;
    int t = threadIdx.x;
    __shared__ float pqs[16][132];
    __shared__ float pks[32][132];

    const float* pqh = pq + ((size_t)h * 1024 + q0) * 128;
    const float* pkh = pk + (size_t)h * 1024 * 128;

#pragma unroll
    for (int u = 0; u < 2; ++u) {
        int f4 = t + u * 256;
        int row = f4 >> 5, dg = (f4 & 31) * 4;
        *(float4*)(&pqs[row][dg]) = *(const float4*)(pqh + (size_t)row * 128 + dg);
    }

    int i = t >> 4, jj = t & 15;
    int qrow = q0 + i;
    unsigned int vals[64];

#pragma unroll
    for (int c = 0; c < 32; ++c) {
        __syncthreads();
#pragma unroll
        for (int u = 0; u < 4; ++u) {
            int f4 = t + u * 256;
            int row = f4 >> 5, dg = (f4 & 31) * 4;
            *(float4*)(&pks[row][dg]) = *(const float4*)(pkh + (size_t)(c * 32 + row) * 128 + dg);
        }
        __syncthreads();
        float s0 = 0.f, s1 = 0.f;
#pragma unroll
        for (int d = 0; d < 128; d += 4) {
            float4 a  = *(const float4*)(&pqs[i][d]);
            float4 b0 = *(const float4*)(&pks[jj][d]);
            float4 b1 = *(const float4*)(&pks[jj + 16][d]);
            s0 += a.x * b0.x + a.y * b0.y + a.z * b0.z + a.w * b0.w;
            s1 += a.x * b1.x + a.y * b1.y + a.z * b1.z + a.w * b1.w;
        }
        int j0 = c * 32 + jj, j1 = j0 + 16;
        vals[2 * c]     = fkey(j0 <= qrow ? s0 : NEGBIG);
        vals[2 * c + 1] = fkey(j1 <= qrow ? s1 : NEGBIG);
    }

    unsigned int p = 0u;
    int kth = 512;
    for (int b = 31; b >= 0; --b) {
        unsigned int bit = 1u << b;
        unsigned int himask = (b == 31) ? 0u : (0xFFFFFFFFu << (b + 1));
        int cnt = 0;
#pragma unroll
        for (int n = 0; n < 64; ++n)
            cnt += (int)((((vals[n] ^ p) & himask) == 0u) && ((vals[n] & bit) != 0u));
        cnt += __shfl_xor(cnt, 1);
        cnt += __shfl_xor(cnt, 2);
        cnt += __shfl_xor(cnt, 4);
        cnt += __shfl_xor(cnt, 8);
        if (cnt >= kth) p |= bit; else kth -= cnt;
    }

    unsigned long long wpart[16];
#pragma unroll
    for (int w = 0; w < 16; ++w) wpart[w] = 0ull;
#pragma unroll
    for (int n = 0; n < 64; ++n) {
        int w = n >> 2;
        int bpos = jj + ((n & 3) << 4);
        wpart[w] |= ((unsigned long long)(vals[n] >= p)) << bpos;
    }
#pragma unroll
    for (int s = 1; s < 16; s <<= 1) {
#pragma unroll
        for (int w = 0; w < 16; ++w)
            wpart[w] |= __shfl_xor(wpart[w], s);
    }
    mask[((size_t)h * 1024 + qrow) * 16 + jj] = wpart[jj];
}

// ---------------- MFMA flash attention, swapped QK^T -----------------------
// block = (interleaved qtile of 64 rows, head); 4 waves x 16 q-rows each.
// S^T = K*Q^T (lane owns q-row = lane&15); O^T = V^T*P^T.
#define ATTN_KP 136   // u16 pitch of K rows (272B)
#define ATTN_VP 40    // u16 pitch of vT rows (80B)

__global__ __launch_bounds__(256) void attn_mfma_kernel(
    const u16* __restrict__ qr,   // [32][1024][128], pre-scaled
    const u16* __restrict__ kr,   // [8][1024][128]
    const u16* __restrict__ vT,   // [8][128][1024]
    const unsigned long long* __restrict__ mask,
    u16* __restrict__ attn)       // [1024][4096]
{
    int bx = blockIdx.x;
    int qt = (bx & 1) ? (bx >> 1) : (15 - (bx >> 1));  // heavy/light interleave
    int h = blockIdx.y;
    int kvh = h >> 2;
    int q0 = qt * 64;
    int t = threadIdx.x;
    int wave = t >> 6, lane = t & 63;
    int fr = lane & 15, fq = lane >> 4;
    int qrow = q0 + wave * 16 + fr;

    __shared__ u16 Ks[32 * ATTN_KP];
    __shared__ u16 Vs[128 * ATTN_VP];

    bf16x8 qf[4];
    const u16* qbase = qr + ((size_t)h * 1024 + qrow) * 128 + fq * 8;
#pragma unroll
    for (int kc = 0; kc < 4; ++kc)
        qf[kc] = *(const bf16x8*)(qbase + kc * 32);

    float m_run = -3.0e38f, l_run = 0.f;
    f32x4 accO[8];
#pragma unroll
    for (int m2 = 0; m2 < 8; ++m2) accO[m2] = 0.f;

    const unsigned long long* mrow = mask + ((size_t)h * 1024 + qrow) * 16;
    const u16* kgh = kr + (size_t)kvh * 1024 * 128;
    const u16* vgh = vT + (size_t)kvh * 128 * 1024;

    int ntiles = (q0 + 64) >> 5;
    for (int c = 0; c < ntiles; ++c) {
        int kv0 = c * 32;
        __syncthreads();
        // stage K [32][128] (pitch 136 u16) and vT [128][32] (pitch 40 u16)
#pragma unroll
        for (int u = 0; u < 2; ++u) {
            int e = t + u * 256;
            int row = e >> 4, bc = (e & 15) * 8;
            uint4 d4 = *(const uint4*)(kgh + ((size_t)(kv0 + row)) * 128 + bc);
            *(uint4*)(&Ks[row * ATTN_KP + bc]) = d4;
        }
#pragma unroll
        for (int u = 0; u < 2; ++u) {
            int e = t + u * 256;
            int row = e >> 2, bc = (e & 3) * 8;
            uint4 d4 = *(const uint4*)(vgh + (size_t)row * 1024 + kv0 + bc);
            *(uint4*)(&Vs[row * ATTN_VP + bc]) = d4;
        }
        __syncthreads();

        // S^T: lane (fr,fq) gets S^T[kv = t2*16 + fq*4 + j][q-row fr]
        f32x4 accS[2];
        accS[0] = 0.f; accS[1] = 0.f;
#pragma unroll
        for (int t2 = 0; t2 < 2; ++t2)
#pragma unroll
            for (int kc = 0; kc < 4; ++kc) {
                bf16x8 kf = *(const bf16x8*)(&Ks[(t2 * 16 + fr) * ATTN_KP + kc * 32 + fq * 8]);
                accS[t2] = __builtin_amdgcn_mfma_f32_16x16x32_bf16(kf, qf[kc], accS[t2], 0, 0, 0);
            }

        // causal + topk mask, online softmax (per-lane q-row)
        unsigned long long mw = mrow[kv0 >> 6];
        int mshift = kv0 & 32;
        float p[2][4];
        float tmax = -3.0e38f;
#pragma unroll
        for (int t2 = 0; t2 < 2; ++t2)
#pragma unroll
            for (int j = 0; j < 4; ++j) {
                int kvi = (fq << 2) + (t2 << 4) + j;
                bool ok = ((mw >> (mshift + kvi)) & 1ull) && (kv0 + kvi <= qrow);
                float s = ok ? accS[t2][j] : -3.0e38f;
                p[t2][j] = s;
                tmax = fmaxf(tmax, s);
            }
        tmax = fmaxf(tmax, __shfl_xor(tmax, 16));
        tmax = fmaxf(tmax, __shfl_xor(tmax, 32));
        float m_new = fmaxf(m_run, tmax);
        float sf = __expf(m_run - m_new);
        float psum = 0.f;
#pragma unroll
        for (int t2 = 0; t2 < 2; ++t2)
#pragma unroll
            for (int j = 0; j < 4; ++j) {
                float e = (p[t2][j] > -1.0e38f) ? __expf(p[t2][j] - m_new) : 0.f;
                p[t2][j] = e;
                psum += e;
            }
        psum += __shfl_xor(psum, 16);
        psum += __shfl_xor(psum, 32);
        l_run = l_run * sf + psum;
        m_run = m_new;

#pragma unroll
        for (int m2 = 0; m2 < 8; ++m2) accO[m2] *= sf;

        // P -> bf16 B-fragment. Lane (fr,fq) holds, pre-shuffle:
        //   W0=(kv 4fq+0,1) W1=(kv 4fq+2,3) [t2=0]; W2,W3 same for t2=1 (+16).
        // Dest lane (fr,fq) needs kv 8fq..8fq+7 for q-row fr:
        //   from src lanes fq'=2(fq&1) [srcA] and fq'=2(fq&1)+1 [srcB],
        //   words W0/W1 if fq<2 (t2=0) else W2/W3 — select on DEST after shfl.
        unsigned W0, W1, W2, W3;
        asm("v_cvt_pk_bf16_f32 %0, %1, %2" : "=v"(W0) : "v"(p[0][0]), "v"(p[0][1]));
        asm("v_cvt_pk_bf16_f32 %0, %1, %2" : "=v"(W1) : "v"(p[0][2]), "v"(p[0][3]));
        asm("v_cvt_pk_bf16_f32 %0, %1, %2" : "=v"(W2) : "v"(p[1][0]), "v"(p[1][1]));
        asm("v_cvt_pk_bf16_f32 %0, %1, %2" : "=v"(W3) : "v"(p[1][2]), "v"(p[1][3]));
        int srcA = fr + ((fq & 1) << 5);
        int srcB = srcA + 16;
        unsigned a0 = __shfl(W0, srcA), a1 = __shfl(W1, srcA);
        unsigned a2 = __shfl(W2, srcA), a3 = __shfl(W3, srcA);
        unsigned b0 = __shfl(W0, srcB), b1 = __shfl(W1, srcB);
        unsigned b2 = __shfl(W2, srcB), b3 = __shfl(W3, srcB);
        bool hi = (fq & 2) != 0;
        union { uint4 u; bf16x8 b; } pc;
        pc.u.x = hi ? a2 : a0;
        pc.u.y = hi ? a3 : a1;
        pc.u.z = hi ? b2 : b0;
        pc.u.w = hi ? b3 : b1;

        // O^T += V^T * P^T
#pragma unroll
        for (int m2 = 0; m2 < 8; ++m2) {
            bf16x8 vf = *(const bf16x8*)(&Vs[(m2 * 16 + fr) * ATTN_VP + fq * 8]);
            accO[m2] = __builtin_amdgcn_mfma_f32_16x16x32_bf16(vf, pc.b, accO[m2], 0, 0, 0);
        }
    }

    float il = 1.0f / l_run;
    u16* obase = attn + (size_t)qrow * 4096 + h * 128 + fq * 4;
#pragma unroll
    for (int m2 = 0; m2 < 8; ++m2) {
        uint2 st;
        st.x = (unsigned)f2b(accO[m2][0] * il) | ((unsigned)f2b(accO[m2][1] * il) << 16);
        st.y = (unsigned)f2b(accO[m2][2] * il) | ((unsigned)f2b(accO[m2][3] * il) << 16);
        *(uint2*)(obase + m2 * 16) = st;
    }
}

extern "C" void kernel_launch(void* const* d_in, const int* in_sizes, int n_in,
                              void* d_out, int out_size, void* d_ws, size_t ws_size,
                              hipStream_t stream)
{
    (void)in_sizes; (void)n_in; (void)out_size; (void)ws_size;
    const float* hs   = (const float*)d_in[0];
    const float* wq   = (const float*)d_in[1];
    const float* wk   = (const float*)d_in[2];
    const float* wv   = (const float*)d_in[3];
    const float* wo   = (const float*)d_in[4];
    const float* mixq = (const float*)d_in[5];
    const float* mixk = (const float*)d_in[6];
    const float* qpos = (const float*)d_in[7];
    const float* kpos = (const float*)d_in[8];
    float* out = (float*)d_out;

    // workspace layout (time-aliased; high-water ~88 MB)
    float* ws   = (float*)d_ws;
    float* qb   = ws;                     // 4M f32
    float* kb   = qb + 4194304;           // 1M
    float* vb   = kb + 1048576;           // 1M
    float* pq   = vb + 1048576;           // 4M } phase1: wqT; phase2: pq;
    float* pk   = pq + 4194304;           // 4M } phase3: qr/kr/vT; phase4: woT
    float* lrq  = pk + 4194304;
    float* lrk  = lrq + 32768;
    float* cosb = lrk + 32768;
    float* sinb = cosb + 65536;
    unsigned long long* mask = (unsigned long long*)(sinb + 65536); // 512K u64
    u16* hs_bf = (u16*)(ws + 14876672 + 1048576);  // 4M u16 (later attn_bf)
    u16* wkT   = hs_bf + 4194304;                  // 4M u16
    u16* wvT   = wkT + 4194304;                    // 4M u16
    u16* wqT   = (u16*)pq;                         // 16M u16 (alias, phase1)
    u16* woT   = (u16*)pq;                         // 16M u16 (alias, phase4)
    u16* qr_bf = (u16*)pq;                         // 4M u16 (alias, phase3)
    u16* kr_bf = (u16*)pk;                         // 1M u16 (alias, phase3)
    u16* vT_bf = (u16*)(pk + 1048576);             // 1M u16 (alias, phase3)
    u16* attn_bf = hs_bf;                          // alias (hs_bf dead by then)

    hipLaunchKernelGGL(rope_tables_kernel, dim3(1024), dim3(64), 0, stream, cosb, sinb);
    hipLaunchKernelGGL(conv_bf16_kernel, dim3(4096), dim3(256), 0, stream, hs, hs_bf);
    hipLaunchKernelGGL(transpose_bf16_kernel, dim3(64, 64), dim3(256), 0, stream, wq, wqT, 4096, 4096);
    hipLaunchKernelGGL(transpose_bf16_kernel, dim3(16, 64), dim3(256), 0, stream, wk, wkT, 4096, 1024);
    hipLaunchKernelGGL(transpose_bf16_kernel, dim3(16, 64), dim3(256), 0, stream, wv, wvT, 4096, 1024);
    hipLaunchKernelGGL(gemm_qkv_bf16_kernel, dim3(48, 8), dim3(256), 0, stream,
                       hs_bf, wqT, wkT, wvT, qb, kb, vb);
    hipLaunchKernelGGL(lr_kernel, dim3(1024), dim3(256), 0, stream, hs, mixq, mixk, lrq, lrk);
    hipLaunchKernelGGL(ppos_kernel, dim3(32, 1024), dim3(128), 0, stream, lrq, qpos, pq);
    hipLaunchKernelGGL(ppos_kernel, dim3(32, 1024), dim3(128), 0, stream, lrk, kpos, pk);
    hipLaunchKernelGGL(draft_select_kernel, dim3(64, 32), dim3(256), 0, stream, pq, pk, mask);
    // pq/pk now dead -> reuse for RoPE'd bf16 q/k and transposed v
    hipLaunchKernelGGL(rope_pack_kernel, dim3(1024, 32), dim3(128), 0, stream,
                       qb, 4096, cosb, sinb, qr_bf, 0.08838834764831845f);
    hipLaunchKernelGGL(rope_pack_kernel, dim3(1024, 8), dim3(128), 0, stream,
                       kb, 1024, cosb, sinb, kr_bf, 1.0f);
    hipLaunchKernelGGL(transpose_bf16_kernel, dim3(16, 16), dim3(256), 0, stream, vb, vT_bf, 1024, 1024);
    hipLaunchKernelGGL(attn_mfma_kernel, dim3(16, 32), dim3(256), 0, stream,
                       qr_bf, kr_bf, vT_bf, mask, attn_bf);
    hipLaunchKernelGGL(transpose_bf16_kernel, dim3(64, 64), dim3(256), 0, stream, wo, woT, 4096, 4096);
    hipLaunchKernelGGL(gemm_wo_bf16_kernel, dim3(32, 8), dim3(256), 0, stream,
                       attn_bf, woT, out);
}